// Round 1
// baseline (368.921 us; speedup 1.0000x reference)
//
#include <hip/hip_runtime.h>

// AcceptRejectPooling2D, inference mode:
//   r = relu(x); per 2x2 window: s = sum(r), ss = sum(r*r); out = s>0 ? ss/s : 0
// Shapes: x (64,64,64,256) f32 NHWC -> out (64,32,32,256) f32.
// Memory-bound: 256 MiB in + 64 MiB out, every input read exactly once.

#define B_  64
#define H_  64
#define W_  64
#define C_  256
#define OH_ (H_/2)
#define OW_ (W_/2)
// float4 granularity: 64 float4 per channel row
#define C4_ (C_/4)
// total output float4 elements
#define N4_ (B_*OH_*OW_*C4_)

__device__ __forceinline__ float arp_comp(float a, float b, float c, float d) {
    a = fmaxf(a, 0.0f);
    b = fmaxf(b, 0.0f);
    c = fmaxf(c, 0.0f);
    d = fmaxf(d, 0.0f);
    float s  = (a + b) + (c + d);
    float ss = (a*a + b*b) + (c*c + d*d);
    return s > 0.0f ? ss / s : 0.0f;
}

__global__ void arp2d_kernel(const float* __restrict__ in, float* __restrict__ out) {
    int idx    = blockIdx.x * blockDim.x + threadIdx.x;
    int stride = gridDim.x * blockDim.x;
    const float4* in4  = reinterpret_cast<const float4*>(in);
    float4*       out4 = reinterpret_cast<float4*>(out);

    for (int i = idx; i < N4_; i += stride) {
        int c4 = i & (C4_ - 1);          // 0..63
        int t  = i >> 6;
        int ow = t & (OW_ - 1);          // 0..31
        t >>= 5;
        int oh = t & (OH_ - 1);          // 0..31
        int b  = t >> 5;                 // 0..63

        // base float4 index of (b, 2*oh, 2*ow, c4*4)
        const float4* base = in4 + ((size_t)((b * H_ + 2*oh) * W_ + 2*ow) * C4_ + c4);
        float4 x0 = base[0];                 // (2oh,   2ow  )
        float4 x1 = base[C4_];               // (2oh,   2ow+1)
        float4 x2 = base[W_ * C4_];          // (2oh+1, 2ow  )
        float4 x3 = base[W_ * C4_ + C4_];    // (2oh+1, 2ow+1)

        float4 o;
        o.x = arp_comp(x0.x, x1.x, x2.x, x3.x);
        o.y = arp_comp(x0.y, x1.y, x2.y, x3.y);
        o.z = arp_comp(x0.z, x1.z, x2.z, x3.z);
        o.w = arp_comp(x0.w, x1.w, x2.w, x3.w);
        out4[i] = o;
    }
}

extern "C" void kernel_launch(void* const* d_in, const int* in_sizes, int n_in,
                              void* d_out, int out_size, void* d_ws, size_t ws_size,
                              hipStream_t stream) {
    const float* x = (const float*)d_in[0];
    float* out = (float*)d_out;

    const int block = 256;
    // memory-bound: cap grid at ~8 blocks/CU * 256 CU and grid-stride the rest
    const int grid = 2048;
    arp2d_kernel<<<grid, block, 0, stream>>>(x, out);
}

// Round 6
// 368.595 us; speedup vs baseline: 1.0009x; 1.0009x over previous
//
#include <hip/hip_runtime.h>

// AcceptRejectPooling2D, inference mode:
//   r = relu(x); per 2x2 window: s = sum(r), ss = sum(r*r); out = s>0 ? ss/s : 0
// Shapes: x (64,64,64,256) f32 NHWC -> out (64,32,32,256) f32.
// Memory-bound: 256 MiB in + 64 MiB out read/written exactly once -> ~51 us floor @6.3 TB/s.
// R1 post-mortem: dur_us includes ~265 us of harness re-poison fills (1 GiB d_ws fill
// = 162 us visible in rocprof top-5); kernel itself ~100 us. This round: exact-trip
// unrolled loop (ILP for 32 outstanding dwordx4) + fast rcp instead of precise divide.
// Nontemporal hints removed: every bench attempt with them hit container failures
// (R2-R5); breaking the source correlation, and they were marginal anyway (input
// 256 MiB >> 32 MiB aggregate L2, streaming data self-evicts).

#define B_  64
#define H_  64
#define W_  64
#define C_  256
#define OH_ (H_/2)
#define OW_ (W_/2)
#define C4_ (C_/4)                 // 64 float4 per (b,h,w) row
#define N4_ (B_*OH_*OW_*C4_)       // 4,194,304 output float4
#define BLOCK 256
#define GRID  2048
#define ITER  (N4_/(BLOCK*GRID))   // exactly 8, no tail

__device__ __forceinline__ float arp_comp(float a, float b, float c, float d) {
    a = fmaxf(a, 0.0f);
    b = fmaxf(b, 0.0f);
    c = fmaxf(c, 0.0f);
    d = fmaxf(d, 0.0f);
    float s  = (a + b) + (c + d);
    float ss = fmaf(a, a, fmaf(b, b, fmaf(c, c, d * d)));
    // v_rcp_f32 (~1 ulp) instead of precise-divide chain; threshold 0.104 >> error
    return s > 0.0f ? ss * __builtin_amdgcn_rcpf(s) : 0.0f;
}

__global__ __launch_bounds__(BLOCK) void arp2d_kernel(const float* __restrict__ in,
                                                      float* __restrict__ out) {
    int tid = blockIdx.x * BLOCK + threadIdx.x;
    const float4* in4  = reinterpret_cast<const float4*>(in);
    float4*       out4 = reinterpret_cast<float4*>(out);

#pragma unroll
    for (int k = 0; k < ITER; ++k) {
        int i  = tid + k * (BLOCK * GRID);
        int c4 = i & (C4_ - 1);          // 0..63 — lane index within wave -> coalesced
        int t  = i >> 6;
        int ow = t & (OW_ - 1);          // 0..31
        t >>= 5;
        int oh = t & (OH_ - 1);          // 0..31
        int b  = t >> 5;                 // 0..63

        // base float4 index of (b, 2*oh, 2*ow, c4*4)
        const float4* base = in4 + ((size_t)((b * H_ + 2 * oh) * W_ + 2 * ow) * C4_ + c4);
        float4 x0 = base[0];                 // (2oh,   2ow  )
        float4 x1 = base[C4_];               // (2oh,   2ow+1)
        float4 x2 = base[W_ * C4_];          // (2oh+1, 2ow  )
        float4 x3 = base[W_ * C4_ + C4_];    // (2oh+1, 2ow+1)

        float4 o;
        o.x = arp_comp(x0.x, x1.x, x2.x, x3.x);
        o.y = arp_comp(x0.y, x1.y, x2.y, x3.y);
        o.z = arp_comp(x0.z, x1.z, x2.z, x3.z);
        o.w = arp_comp(x0.w, x1.w, x2.w, x3.w);
        out4[i] = o;
    }
}

extern "C" void kernel_launch(void* const* d_in, const int* in_sizes, int n_in,
                              void* d_out, int out_size, void* d_ws, size_t ws_size,
                              hipStream_t stream) {
    const float* x = (const float*)d_in[0];
    float* out = (float*)d_out;
    arp2d_kernel<<<GRID, BLOCK, 0, stream>>>(x, out);
}